// Round 12
// baseline (399.465 us; speedup 1.0000x reference)
//
#include <hip/hip_runtime.h>
#include <stdint.h>

#define NN 50000
#define NE 800000
#define DD 128
#define NL 3
#define NB_E 200     // edge blocks for hist/bin
#define EPB 4000     // edges per block (NB_E*EPB == NE)
#define NBK 196      // dst buckets = ceil(NN/256), bucket = dst>>8
#define MH (NBK*NB_E)// blkhist elements = 39200
#define LSTR 136     // LDS ushort stride per row (272 B, 16B-aligned)

typedef __attribute__((ext_vector_type(8))) short short8;
typedef __attribute__((ext_vector_type(4))) float f32x4;

// ---------- bf16 helpers ----------
__device__ __forceinline__ float b2f(unsigned short u){
  union { unsigned int i; float f; } v; v.i = ((unsigned int)u) << 16; return v.f;
}
__device__ __forceinline__ unsigned short f2b(float f){
  union { float f; unsigned int i; } v; v.f = f;
  unsigned int r = 0x7FFFu + ((v.i >> 16) & 1u);
  return (unsigned short)((v.i + r) >> 16);
}

// ---------- CSR build: deterministic two-level binning ----------
__global__ __launch_bounds__(256) void k_hist(const int* __restrict__ dst,
                                              int* __restrict__ blkhist){
  __shared__ int h[NBK];
  int t = threadIdx.x, b = blockIdx.x;
  for (int i = t; i < NBK; i += 256) h[i] = 0;
  __syncthreads();
  int e0 = b * EPB;
  for (int i = t; i < EPB; i += 256){
    int d = dst[e0 + i];
    atomicAdd(&h[d >> 8], 1);
  }
  __syncthreads();
  for (int i = t; i < NBK; i += 256) blkhist[i * NB_E + b] = h[i];
}

// single-block exclusive scan over MH elements (1024 thr, 39 elems/thr)
__global__ __launch_bounds__(1024) void k_scan1k(const int* __restrict__ in,
                                                 int* __restrict__ out){
  __shared__ int s[1024];
  int t = threadIdx.x;
  int b0 = t * 39;                 // 39*1024 = 39936 >= MH
  int sum = 0;
  for (int i = 0; i < 39; ++i){
    int ix = b0 + i;
    sum += (ix < MH) ? in[ix] : 0;
  }
  s[t] = sum; __syncthreads();
  for (int d = 1; d < 1024; d <<= 1){
    int x = (t >= d) ? s[t - d] : 0;
    __syncthreads();
    s[t] += x;
    __syncthreads();
  }
  int run = s[t] - sum;            // exclusive prefix of this thread's chunk
  for (int i = 0; i < 39; ++i){
    int ix = b0 + i;
    if (ix < MH){
      int v = in[ix];
      out[ix] = run;
      run += v;
    }
  }
}

__global__ __launch_bounds__(256) void k_bin(const int* __restrict__ src,
    const int* __restrict__ dst, const int* __restrict__ pos,
    unsigned int* __restrict__ binned){
  __shared__ int cur[NBK];
  int t = threadIdx.x, b = blockIdx.x;
  for (int i = t; i < NBK; i += 256) cur[i] = pos[i * NB_E + b];
  __syncthreads();
  int e0 = b * EPB;
  for (int i = t; i < EPB; i += 256){
    int d = dst[e0 + i];
    int s = src[e0 + i];
    int p = atomicAdd(&cur[d >> 8], 1);
    binned[p] = ((unsigned int)d << 16) | (unsigned int)s;
  }
}

__global__ __launch_bounds__(256) void k_csr(const unsigned int* __restrict__ binned,
    const int* __restrict__ pos, int* __restrict__ offs, int* __restrict__ counts,
    int* __restrict__ csr_src){
  __shared__ int h[256], ex[256], cur[256];
  int t = threadIdx.x, b = blockIdx.x;
  int r0 = pos[b * NB_E];
  int r1 = (b == NBK - 1) ? NE : pos[(b + 1) * NB_E];
  h[t] = 0; __syncthreads();
  for (int i = r0 + t; i < r1; i += 256){
    unsigned int pv = binned[i];
    atomicAdd(&h[(pv >> 16) & 255], 1);
  }
  __syncthreads();
  int v = h[t];
  ex[t] = v; __syncthreads();
  for (int d = 1; d < 256; d <<= 1){
    int x = (t >= d) ? ex[t - d] : 0;
    __syncthreads();
    ex[t] += x;
    __syncthreads();
  }
  int base = r0 + ex[t] - v;
  cur[t] = base;
  int gd = b * 256 + t;
  if (gd < NN){ offs[gd] = base; counts[gd] = v; }
  __syncthreads();
  for (int i = r0 + t; i < r1; i += 256){
    unsigned int pv = binned[i];
    int dl = (pv >> 16) & 255;
    int s = pv & 0xFFFF;
    int p = atomicAdd(&cur[dl], 1);
    csr_src[p] = s;
  }
}

// ---------- merged prep: x split + W transpose/split + BN fold ----------
__global__ __launch_bounds__(256) void k_prep(const float* __restrict__ x,
    const float* __restrict__ W1, const float* __restrict__ W2,
    const float* __restrict__ b1, const float* __restrict__ b2,
    const float* __restrict__ g, const float* __restrict__ be,
    const float* __restrict__ rm, const float* __restrict__ rv,
    unsigned short* __restrict__ Shi, unsigned short* __restrict__ Slo,
    unsigned short* __restrict__ Wthi, unsigned short* __restrict__ Wtlo,
    float* __restrict__ sc, float* __restrict__ sh){
  int idx = blockIdx.x * 256 + threadIdx.x;   // grid = NN*DD/8/256 = 3125 blocks
  // x -> hi/lo (8 elems/thread)
  {
    float4 a = ((const float4*)x)[2 * idx];
    float4 b = ((const float4*)x)[2 * idx + 1];
    float v[8] = {a.x, a.y, a.z, a.w, b.x, b.y, b.z, b.w};
    short8 h8, l8;
    #pragma unroll
    for (int c = 0; c < 8; ++c){
      unsigned short h = f2b(v[c]);
      h8[c] = (short)h; l8[c] = (short)f2b(v[c] - b2f(h));
    }
    ((short8*)Shi)[idx] = h8;
    ((short8*)Slo)[idx] = l8;
  }
  // W transpose + split (98304 = 6*128*128)
  if (idx < 6 * DD * DD){
    int mat = idx >> 14;
    int rem = idx & 16383;
    int k = rem >> 7, j = rem & 127;
    int layer = mat >> 1, which = mat & 1;
    const float* srcW = which ? W2 : W1;
    float w = srcW[layer * 16384 + k * DD + j];
    unsigned short hi = f2b(w);
    Wthi[mat * 16384 + j * DD + k] = hi;
    Wtlo[mat * 16384 + j * DD + k] = f2b(w - b2f(hi));
  }
  // BN fold (768 = 3*2*128)
  if (idx < NL * 2 * DD){
    int j = idx & 127;
    int w2 = (idx >> 7) & 1;
    int l = idx >> 8;
    int p = (l * 2 + w2) * DD + j;
    float s = g[p] * rsqrtf(rv[p] + 1e-5f);
    float bias = w2 ? b2[l * DD + j] : b1[l * DD + j];
    sc[p] = s;
    sh[p] = fmaf(bias - rm[p], s, be[p]);
  }
}

// ---------- aggregate (standalone, max occupancy): 16 lanes/row, 8-nbr unroll ----------
__global__ __launch_bounds__(256, 8) void k_agg(
    const unsigned short* __restrict__ Shi, const unsigned short* __restrict__ Slo,
    const int* __restrict__ offs, const int* __restrict__ counts,
    const int* __restrict__ csr_src,
    unsigned short* __restrict__ Ahi, unsigned short* __restrict__ Alo){
  int t = blockIdx.x * 256 + threadIdx.x;
  int row = t >> 4;                // grid 3125 covers exactly NN
  int l = t & 15;
  const short8* H = (const short8*)Shi;   // [row][16]
  const short8* L = (const short8*)Slo;
  int idx = row * 16 + l;
  short8 s_h = H[idx]; short8 s_l = L[idx];
  float acc[8];
  #pragma unroll
  for (int i = 0; i < 8; ++i)
    acc[i] = b2f((unsigned short)s_h[i]) + b2f((unsigned short)s_l[i]);

  int e = offs[row];
  int end = e + counts[row];
  for (; e + 8 <= end; e += 8){
    int i0 = csr_src[e],   i1 = csr_src[e+1], i2 = csr_src[e+2], i3 = csr_src[e+3];
    int i4 = csr_src[e+4], i5 = csr_src[e+5], i6 = csr_src[e+6], i7 = csr_src[e+7];
    short8 g0 = H[i0*16+l], g1 = H[i1*16+l], g2 = H[i2*16+l], g3 = H[i3*16+l];
    short8 g4 = H[i4*16+l], g5 = H[i5*16+l], g6 = H[i6*16+l], g7 = H[i7*16+l];
    #pragma unroll
    for (int i = 0; i < 8; ++i){
      acc[i] += (b2f((unsigned short)g0[i]) + b2f((unsigned short)g1[i]))
              + (b2f((unsigned short)g2[i]) + b2f((unsigned short)g3[i]))
              + (b2f((unsigned short)g4[i]) + b2f((unsigned short)g5[i]))
              + (b2f((unsigned short)g6[i]) + b2f((unsigned short)g7[i]));
    }
  }
  for (; e < end; ++e){
    short8 g0 = H[csr_src[e]*16 + l];
    #pragma unroll
    for (int i = 0; i < 8; ++i) acc[i] += b2f((unsigned short)g0[i]);
  }

  short8 oh, ol;
  #pragma unroll
  for (int i = 0; i < 8; ++i){
    unsigned short h = f2b(acc[i]);
    oh[i] = (short)h; ol[i] = (short)f2b(acc[i] - b2f(h));
  }
  ((short8*)Ahi)[idx] = oh;
  ((short8*)Alo)[idx] = ol;
}

// ---------- fused MLP v5: 128-thr block = 2 waves; 32 rows x 64 cols per wave ----------
// 1563 blocks (2x round-11 grid) for occupancy; A direct from global; LDS only for
// H handoff (17.4 KB). 8 acc chains/wave, 12 loads per kc group.
template<int LAST>
__global__ __launch_bounds__(128, 4) void k_mlp(
    const unsigned short* __restrict__ Ahi, const unsigned short* __restrict__ Alo,
    const unsigned short* __restrict__ W1h, const unsigned short* __restrict__ W1l,
    const unsigned short* __restrict__ W2h, const unsigned short* __restrict__ W2l,
    const float* __restrict__ sc1, const float* __restrict__ sh1,
    const float* __restrict__ sc2, const float* __restrict__ sh2,
    unsigned short* __restrict__ Ohi, unsigned short* __restrict__ Olo,
    float* __restrict__ Of)
{
  __shared__ __align__(16) char smem[2 * 32 * LSTR * 2];   // 17,408 B
  unsigned short* Hhi_s = (unsigned short*)smem;
  unsigned short* Hlo_s = Hhi_s + 32 * LSTR;

  int t = threadIdx.x;
  int base = blockIdx.x * 32;
  int wave = t >> 6, lane = t & 63, l16 = lane & 15, q = lane >> 4;
  int c0 = wave * 64;            // this wave's 64 output cols

  const short8* AH = (const short8*)Ahi;    // [row][16]
  const short8* AL = (const short8*)Alo;
  const short8* B1H = (const short8*)W1h;   // [j][16]
  const short8* B1L = (const short8*)W1l;
  const short8* B2H = (const short8*)W2h;
  const short8* B2L = (const short8*)W2l;

  int ar[2];
  #pragma unroll
  for (int rt = 0; rt < 2; ++rt){
    int r = base + rt * 16 + l16;
    ar[rt] = (r > NN - 1) ? (NN - 1) : r;
  }

  // ---- gemm1: A direct from global, W1 from global/L2 ----
  f32x4 acc[2][4];
  #pragma unroll
  for (int rt = 0; rt < 2; ++rt)
    #pragma unroll
    for (int ct = 0; ct < 4; ++ct) acc[rt][ct] = (f32x4){0.f, 0.f, 0.f, 0.f};

  #pragma unroll
  for (int kc = 0; kc < 4; ++kc){
    short8 ah[2], al[2], bh[4], bl[4];
    #pragma unroll
    for (int rt = 0; rt < 2; ++rt){
      ah[rt] = AH[ar[rt] * 16 + kc * 4 + q];
      al[rt] = AL[ar[rt] * 16 + kc * 4 + q];
    }
    #pragma unroll
    for (int ct = 0; ct < 4; ++ct){
      int wr = c0 + ct * 16 + l16;
      bh[ct] = B1H[wr * 16 + kc * 4 + q];
      bl[ct] = B1L[wr * 16 + kc * 4 + q];
    }
    #pragma unroll
    for (int rt = 0; rt < 2; ++rt)
      #pragma unroll
      for (int ct = 0; ct < 4; ++ct){
        acc[rt][ct] = __builtin_amdgcn_mfma_f32_16x16x32_bf16(ah[rt], bh[ct], acc[rt][ct], 0, 0, 0);
        acc[rt][ct] = __builtin_amdgcn_mfma_f32_16x16x32_bf16(ah[rt], bl[ct], acc[rt][ct], 0, 0, 0);
        acc[rt][ct] = __builtin_amdgcn_mfma_f32_16x16x32_bf16(al[rt], bh[ct], acc[rt][ct], 0, 0, 0);
      }
  }

  // ---- BN1 + ReLU -> H into LDS (hi/lo split) ----
  #pragma unroll
  for (int ct = 0; ct < 4; ++ct){
    int col = c0 + ct * 16 + l16;
    float s = sc1[col], b = sh1[col];
    #pragma unroll
    for (int rt = 0; rt < 2; ++rt)
      #pragma unroll
      for (int r = 0; r < 4; ++r){
        int rl = rt * 16 + q * 4 + r;       // C/D layout: row=(lane>>4)*4+reg
        float v = fmaxf(fmaf(acc[rt][ct][r], s, b), 0.f);
        unsigned short h = f2b(v);
        Hhi_s[rl * LSTR + col] = h;
        Hlo_s[rl * LSTR + col] = f2b(v - b2f(h));
      }
  }
  __syncthreads();   // H ready (both waves' column halves)

  // ---- gemm2: H from LDS, W2 from global/L2 ----
  f32x4 acc2[2][4];
  #pragma unroll
  for (int rt = 0; rt < 2; ++rt)
    #pragma unroll
    for (int ct = 0; ct < 4; ++ct) acc2[rt][ct] = (f32x4){0.f, 0.f, 0.f, 0.f};

  #pragma unroll
  for (int kc = 0; kc < 4; ++kc){
    short8 ah[2], al[2], bh[4], bl[4];
    #pragma unroll
    for (int rt = 0; rt < 2; ++rt){
      ah[rt] = *(const short8*)&Hhi_s[(rt * 16 + l16) * LSTR + kc * 32 + q * 8];
      al[rt] = *(const short8*)&Hlo_s[(rt * 16 + l16) * LSTR + kc * 32 + q * 8];
    }
    #pragma unroll
    for (int ct = 0; ct < 4; ++ct){
      int wr = c0 + ct * 16 + l16;
      bh[ct] = B2H[wr * 16 + kc * 4 + q];
      bl[ct] = B2L[wr * 16 + kc * 4 + q];
    }
    #pragma unroll
    for (int rt = 0; rt < 2; ++rt)
      #pragma unroll
      for (int ct = 0; ct < 4; ++ct){
        acc2[rt][ct] = __builtin_amdgcn_mfma_f32_16x16x32_bf16(ah[rt], bh[ct], acc2[rt][ct], 0, 0, 0);
        acc2[rt][ct] = __builtin_amdgcn_mfma_f32_16x16x32_bf16(ah[rt], bl[ct], acc2[rt][ct], 0, 0, 0);
        acc2[rt][ct] = __builtin_amdgcn_mfma_f32_16x16x32_bf16(al[rt], bh[ct], acc2[rt][ct], 0, 0, 0);
      }
  }
  __syncthreads();   // both waves done reading H; LDS reusable for staging

  // ---- epilogue: BN2 + ReLU; wave-private col-half staging, coalesced store ----
  if (!LAST){
    #pragma unroll
    for (int ct = 0; ct < 4; ++ct){
      int col = c0 + ct * 16 + l16;
      float s = sc2[col], b = sh2[col];
      #pragma unroll
      for (int rt = 0; rt < 2; ++rt)
        #pragma unroll
        for (int r = 0; r < 4; ++r){
          int rl = rt * 16 + q * 4 + r;
          float v = fmaxf(fmaf(acc2[rt][ct][r], s, b), 0.f);
          unsigned short h = f2b(v);
          Hhi_s[rl * LSTR + col] = h;
          Hlo_s[rl * LSTR + col] = f2b(v - b2f(h));
        }
    }
    // wave-private readback: 32 rows x own 64-col half
    int rr = lane >> 3, ch = lane & 7;
    #pragma unroll
    for (int i = 0; i < 4; ++i){
      int rl = i * 8 + rr;
      int rg = base + rl;
      short8 vh = *(const short8*)&Hhi_s[rl * LSTR + c0 + ch * 8];
      short8 vl = *(const short8*)&Hlo_s[rl * LSTR + c0 + ch * 8];
      if (rg < NN){
        *(short8*)&Ohi[rg * DD + c0 + ch * 8] = vh;
        *(short8*)&Olo[rg * DD + c0 + ch * 8] = vl;
      }
    }
  } else {
    float* Cf = (float*)smem;      // 32 x 132 floats = 16,896 B (fits)
    #pragma unroll
    for (int ct = 0; ct < 4; ++ct){
      int col = c0 + ct * 16 + l16;
      float s = sc2[col], b = sh2[col];
      #pragma unroll
      for (int rt = 0; rt < 2; ++rt)
        #pragma unroll
        for (int r = 0; r < 4; ++r){
          int rl = rt * 16 + q * 4 + r;
          Cf[rl * 132 + col] = fmaxf(fmaf(acc2[rt][ct][r], s, b), 0.f);
        }
    }
    int rr = lane >> 4, cf = (lane & 15) * 4;
    #pragma unroll
    for (int i = 0; i < 8; ++i){
      int rl = i * 4 + rr;
      int rg = base + rl;
      float4 v = *(const float4*)&Cf[rl * 132 + c0 + cf];
      if (rg < NN) *(float4*)&Of[rg * DD + c0 + cf] = v;
    }
  }
}

// ---------- launch ----------
extern "C" void kernel_launch(void* const* d_in, const int* in_sizes, int n_in,
                              void* d_out, int out_size, void* d_ws, size_t ws_size,
                              hipStream_t stream) {
  const float* x  = (const float*)d_in[0];
  const int* ei   = (const int*)d_in[1];
  const float* W1 = (const float*)d_in[2];
  const float* b1 = (const float*)d_in[3];
  const float* W2 = (const float*)d_in[4];
  const float* b2 = (const float*)d_in[5];
  const float* g  = (const float*)d_in[6];
  const float* be = (const float*)d_in[7];
  const float* rm = (const float*)d_in[8];
  const float* rv = (const float*)d_in[9];

  const int* src = ei;
  const int* dst = ei + NE;

  char* w = (char*)d_ws;
  const size_t HB = (size_t)NN * DD * sizeof(unsigned short);  // 12.8 MB
  unsigned short* S0hi = (unsigned short*)w; w += HB;
  unsigned short* S0lo = (unsigned short*)w; w += HB;
  unsigned short* S1hi = (unsigned short*)w; w += HB;
  unsigned short* S1lo = (unsigned short*)w; w += HB;
  unsigned short* Ahi  = (unsigned short*)w; w += HB;   // agg output
  unsigned short* Alo  = (unsigned short*)w; w += HB;
  unsigned short* Wthi = (unsigned short*)w; w += 6 * 16384 * sizeof(unsigned short);
  unsigned short* Wtlo = (unsigned short*)w; w += 6 * 16384 * sizeof(unsigned short);
  float* scv = (float*)w; w += NL * 2 * DD * sizeof(float);
  float* shv = (float*)w; w += NL * 2 * DD * sizeof(float);
  int* counts  = (int*)w; w += 200192;
  int* offs    = (int*)w; w += 200192;
  int* blkhist = (int*)w; w += MH * sizeof(int);
  int* pos     = (int*)w; w += MH * sizeof(int);
  unsigned int* binned = (unsigned int*)w; w += (size_t)NE * sizeof(unsigned int);
  int* csr_src = (int*)w; w += (size_t)NE * sizeof(int);

  // CSR build: deterministic two-level binning (no cross-XCD line sharing)
  k_hist<<<NB_E, 256, 0, stream>>>(dst, blkhist);
  k_scan1k<<<1, 1024, 0, stream>>>(blkhist, pos);
  k_bin<<<NB_E, 256, 0, stream>>>(src, dst, pos, binned);
  k_csr<<<NBK, 256, 0, stream>>>(binned, pos, offs, counts, csr_src);

  // merged prep: x split + W transpose/split + BN fold
  k_prep<<<NN * DD / 8 / 256, 256, 0, stream>>>(x, W1, W2, b1, b2, g, be, rm, rv,
      S0hi, S0lo, Wthi, Wtlo, scv, shv);

  const int AGG_BLOCKS = NN * 16 / 256;      // 3125
  const int MLP_BLOCKS = (NN + 31) / 32;     // 1563

  for (int i = 0; i < NL; ++i){
    const unsigned short* W1h = Wthi + (size_t)(i * 2 + 0) * 16384;
    const unsigned short* W1l = Wtlo + (size_t)(i * 2 + 0) * 16384;
    const unsigned short* W2h = Wthi + (size_t)(i * 2 + 1) * 16384;
    const unsigned short* W2l = Wtlo + (size_t)(i * 2 + 1) * 16384;
    const float* sc1 = scv + (size_t)(i * 2 + 0) * DD;
    const float* sh1 = shv + (size_t)(i * 2 + 0) * DD;
    const float* sc2 = scv + (size_t)(i * 2 + 1) * DD;
    const float* sh2 = shv + (size_t)(i * 2 + 1) * DD;

    const unsigned short* Ih = (i & 1) ? S1hi : S0hi;
    const unsigned short* Il = (i & 1) ? S1lo : S0lo;
    unsigned short* Oh = (i & 1) ? S0hi : S1hi;
    unsigned short* Ol = (i & 1) ? S0lo : S1lo;

    k_agg<<<AGG_BLOCKS, 256, 0, stream>>>(Ih, Il, offs, counts, csr_src, Ahi, Alo);

    if (i == NL - 1){
      k_mlp<1><<<MLP_BLOCKS, 128, 0, stream>>>(Ahi, Alo,
          W1h, W1l, W2h, W2l, sc1, sh1, sc2, sh2,
          (unsigned short*)nullptr, (unsigned short*)nullptr, (float*)d_out);
    } else {
      k_mlp<0><<<MLP_BLOCKS, 128, 0, stream>>>(Ahi, Alo,
          W1h, W1l, W2h, W2l, sc1, sh1, sc2, sh2, Oh, Ol, (float*)nullptr);
    }
  }
}

// Round 13
// 316.454 us; speedup vs baseline: 1.2623x; 1.2623x over previous
//
#include <hip/hip_runtime.h>
#include <stdint.h>

#define NN 50000
#define NE 800000
#define DD 128
#define NL 3
#define NB_E 200     // edge blocks for hist/bin
#define EPB 4000     // edges per block (NB_E*EPB == NE)
#define NBK 196      // dst buckets = ceil(NN/256), bucket = dst>>8
#define MH (NBK*NB_E)// blkhist elements = 39200
#define LSTR 136     // LDS ushort stride per row (272 B, 16B-aligned)

typedef __attribute__((ext_vector_type(8))) short short8;
typedef __attribute__((ext_vector_type(4))) float f32x4;

// ---------- bf16 helpers ----------
__device__ __forceinline__ float b2f(unsigned short u){
  union { unsigned int i; float f; } v; v.i = ((unsigned int)u) << 16; return v.f;
}
__device__ __forceinline__ unsigned short f2b(float f){
  union { float f; unsigned int i; } v; v.f = f;
  unsigned int r = 0x7FFFu + ((v.i >> 16) & 1u);
  return (unsigned short)((v.i + r) >> 16);
}

// ---------- CSR build: deterministic two-level binning ----------
__global__ __launch_bounds__(256) void k_hist(const int* __restrict__ dst,
                                              int* __restrict__ blkhist){
  __shared__ int h[NBK];
  int t = threadIdx.x, b = blockIdx.x;
  for (int i = t; i < NBK; i += 256) h[i] = 0;
  __syncthreads();
  int e0 = b * EPB;
  for (int i = t; i < EPB; i += 256){
    int d = dst[e0 + i];
    atomicAdd(&h[d >> 8], 1);
  }
  __syncthreads();
  for (int i = t; i < NBK; i += 256) blkhist[i * NB_E + b] = h[i];
}

__global__ void k_scanA(const int* __restrict__ in, int* __restrict__ out,
                        int* __restrict__ bsum, int n){
  __shared__ int s[256];
  int t = threadIdx.x, i = blockIdx.x * 256 + t;
  int v = (i < n) ? in[i] : 0;
  s[t] = v; __syncthreads();
  for (int d = 1; d < 256; d <<= 1){
    int x = (t >= d) ? s[t - d] : 0;
    __syncthreads();
    s[t] += x;
    __syncthreads();
  }
  if (i < n) out[i] = s[t] - v;
  if (t == 255) bsum[blockIdx.x] = s[255];
}

__global__ void k_scanB(int* __restrict__ bsum, int nblk){
  __shared__ int s[256];
  int t = threadIdx.x;
  int v = (t < nblk) ? bsum[t] : 0;
  s[t] = v; __syncthreads();
  for (int d = 1; d < 256; d <<= 1){
    int x = (t >= d) ? s[t - d] : 0;
    __syncthreads();
    s[t] += x;
    __syncthreads();
  }
  if (t < nblk) bsum[t] = s[t] - v;
}

__global__ void k_scanC(int* __restrict__ out, const int* __restrict__ bsum, int n){
  int i = blockIdx.x * 256 + threadIdx.x;
  if (i < n) out[i] += bsum[blockIdx.x];
}

__global__ __launch_bounds__(256) void k_bin(const int* __restrict__ src,
    const int* __restrict__ dst, const int* __restrict__ pos,
    unsigned int* __restrict__ binned){
  __shared__ int cur[NBK];
  int t = threadIdx.x, b = blockIdx.x;
  for (int i = t; i < NBK; i += 256) cur[i] = pos[i * NB_E + b];
  __syncthreads();
  int e0 = b * EPB;
  for (int i = t; i < EPB; i += 256){
    int d = dst[e0 + i];
    int s = src[e0 + i];
    int p = atomicAdd(&cur[d >> 8], 1);
    binned[p] = ((unsigned int)d << 16) | (unsigned int)s;
  }
}

__global__ __launch_bounds__(256) void k_csr(const unsigned int* __restrict__ binned,
    const int* __restrict__ pos, int* __restrict__ offs, int* __restrict__ counts,
    int* __restrict__ csr_src){
  __shared__ int h[256], ex[256], cur[256];
  int t = threadIdx.x, b = blockIdx.x;
  int r0 = pos[b * NB_E];
  int r1 = (b == NBK - 1) ? NE : pos[(b + 1) * NB_E];
  h[t] = 0; __syncthreads();
  for (int i = r0 + t; i < r1; i += 256){
    unsigned int pv = binned[i];
    atomicAdd(&h[(pv >> 16) & 255], 1);
  }
  __syncthreads();
  int v = h[t];
  ex[t] = v; __syncthreads();
  for (int d = 1; d < 256; d <<= 1){
    int x = (t >= d) ? ex[t - d] : 0;
    __syncthreads();
    ex[t] += x;
    __syncthreads();
  }
  int base = r0 + ex[t] - v;
  cur[t] = base;
  int gd = b * 256 + t;
  if (gd < NN){ offs[gd] = base; counts[gd] = v; }
  __syncthreads();
  for (int i = r0 + t; i < r1; i += 256){
    unsigned int pv = binned[i];
    int dl = (pv >> 16) & 255;
    int s = pv & 0xFFFF;
    int p = atomicAdd(&cur[dl], 1);
    csr_src[p] = s;
  }
}

// ---------- merged prep: x split + W transpose/split + BN fold ----------
__global__ __launch_bounds__(256) void k_prep(const float* __restrict__ x,
    const float* __restrict__ W1, const float* __restrict__ W2,
    const float* __restrict__ b1, const float* __restrict__ b2,
    const float* __restrict__ g, const float* __restrict__ be,
    const float* __restrict__ rm, const float* __restrict__ rv,
    unsigned short* __restrict__ Shi, unsigned short* __restrict__ Slo,
    unsigned short* __restrict__ Wthi, unsigned short* __restrict__ Wtlo,
    float* __restrict__ sc, float* __restrict__ sh){
  int idx = blockIdx.x * 256 + threadIdx.x;   // grid = NN*DD/8/256 = 3125 blocks
  // x -> hi/lo (8 elems/thread)
  {
    float4 a = ((const float4*)x)[2 * idx];
    float4 b = ((const float4*)x)[2 * idx + 1];
    float v[8] = {a.x, a.y, a.z, a.w, b.x, b.y, b.z, b.w};
    short8 h8, l8;
    #pragma unroll
    for (int c = 0; c < 8; ++c){
      unsigned short h = f2b(v[c]);
      h8[c] = (short)h; l8[c] = (short)f2b(v[c] - b2f(h));
    }
    ((short8*)Shi)[idx] = h8;
    ((short8*)Slo)[idx] = l8;
  }
  // W transpose + split (98304 = 6*128*128)
  if (idx < 6 * DD * DD){
    int mat = idx >> 14;
    int rem = idx & 16383;
    int k = rem >> 7, j = rem & 127;
    int layer = mat >> 1, which = mat & 1;
    const float* srcW = which ? W2 : W1;
    float w = srcW[layer * 16384 + k * DD + j];
    unsigned short hi = f2b(w);
    Wthi[mat * 16384 + j * DD + k] = hi;
    Wtlo[mat * 16384 + j * DD + k] = f2b(w - b2f(hi));
  }
  // BN fold (768 = 3*2*128)
  if (idx < NL * 2 * DD){
    int j = idx & 127;
    int w2 = (idx >> 7) & 1;
    int l = idx >> 8;
    int p = (l * 2 + w2) * DD + j;
    float s = g[p] * rsqrtf(rv[p] + 1e-5f);
    float bias = w2 ? b2[l * DD + j] : b1[l * DD + j];
    sc[p] = s;
    sh[p] = fmaf(bias - rm[p], s, be[p]);
  }
}

// ---------- aggregate (standalone, max occupancy): 16 lanes/row, 8-nbr unroll ----------
__global__ __launch_bounds__(256, 8) void k_agg(
    const unsigned short* __restrict__ Shi, const unsigned short* __restrict__ Slo,
    const int* __restrict__ offs, const int* __restrict__ counts,
    const int* __restrict__ csr_src,
    unsigned short* __restrict__ Ahi, unsigned short* __restrict__ Alo){
  int t = blockIdx.x * 256 + threadIdx.x;
  int row = t >> 4;                // grid 3125 covers exactly NN
  int l = t & 15;
  const short8* H = (const short8*)Shi;   // [row][16]
  const short8* L = (const short8*)Slo;
  int idx = row * 16 + l;
  short8 s_h = H[idx]; short8 s_l = L[idx];
  float acc[8];
  #pragma unroll
  for (int i = 0; i < 8; ++i)
    acc[i] = b2f((unsigned short)s_h[i]) + b2f((unsigned short)s_l[i]);

  int e = offs[row];
  int end = e + counts[row];
  for (; e + 8 <= end; e += 8){
    int i0 = csr_src[e],   i1 = csr_src[e+1], i2 = csr_src[e+2], i3 = csr_src[e+3];
    int i4 = csr_src[e+4], i5 = csr_src[e+5], i6 = csr_src[e+6], i7 = csr_src[e+7];
    short8 g0 = H[i0*16+l], g1 = H[i1*16+l], g2 = H[i2*16+l], g3 = H[i3*16+l];
    short8 g4 = H[i4*16+l], g5 = H[i5*16+l], g6 = H[i6*16+l], g7 = H[i7*16+l];
    #pragma unroll
    for (int i = 0; i < 8; ++i){
      acc[i] += (b2f((unsigned short)g0[i]) + b2f((unsigned short)g1[i]))
              + (b2f((unsigned short)g2[i]) + b2f((unsigned short)g3[i]))
              + (b2f((unsigned short)g4[i]) + b2f((unsigned short)g5[i]))
              + (b2f((unsigned short)g6[i]) + b2f((unsigned short)g7[i]));
    }
  }
  for (; e < end; ++e){
    short8 g0 = H[csr_src[e]*16 + l];
    #pragma unroll
    for (int i = 0; i < 8; ++i) acc[i] += b2f((unsigned short)g0[i]);
  }

  short8 oh, ol;
  #pragma unroll
  for (int i = 0; i < 8; ++i){
    unsigned short h = f2b(acc[i]);
    oh[i] = (short)h; ol[i] = (short)f2b(acc[i] - b2f(h));
  }
  ((short8*)Ahi)[idx] = oh;
  ((short8*)Alo)[idx] = ol;
}

// ---------- fused MLP (round-11 best): 128-thr block = 2 waves; 64 rows x 64 cols/wave ----------
// gemm1 reads A DIRECT from global (fragment = contiguous 16B). LDS (34.8KB) only for
// H handoff + epilogue staging. 2 barriers total. 16 acc chains/wave.
template<int LAST>
__global__ __launch_bounds__(128, 2) void k_mlp(
    const unsigned short* __restrict__ Ahi, const unsigned short* __restrict__ Alo,
    const unsigned short* __restrict__ W1h, const unsigned short* __restrict__ W1l,
    const unsigned short* __restrict__ W2h, const unsigned short* __restrict__ W2l,
    const float* __restrict__ sc1, const float* __restrict__ sh1,
    const float* __restrict__ sc2, const float* __restrict__ sh2,
    unsigned short* __restrict__ Ohi, unsigned short* __restrict__ Olo,
    float* __restrict__ Of)
{
  __shared__ __align__(16) char smem[2 * 64 * LSTR * 2];   // 34,816 B (H hi/lo; C stage)
  unsigned short* Hhi_s = (unsigned short*)smem;
  unsigned short* Hlo_s = Hhi_s + 64 * LSTR;

  int t = threadIdx.x;
  int base = blockIdx.x * 64;
  int wave = t >> 6, lane = t & 63, l16 = lane & 15, q = lane >> 4;
  int c0 = wave * 64;            // this wave's 64 output cols

  const short8* AH = (const short8*)Ahi;    // [row][16]
  const short8* AL = (const short8*)Alo;
  const short8* B1H = (const short8*)W1h;   // [j][16]
  const short8* B1L = (const short8*)W1l;
  const short8* B2H = (const short8*)W2h;
  const short8* B2L = (const short8*)W2l;

  int ar[4];
  #pragma unroll
  for (int rt = 0; rt < 4; ++rt){
    int r = base + rt * 16 + l16;
    ar[rt] = (r > NN - 1) ? (NN - 1) : r;
  }

  // ---- gemm1: A direct from global, W1 from global/L2 ----
  f32x4 acc[4][4];
  #pragma unroll
  for (int rt = 0; rt < 4; ++rt)
    #pragma unroll
    for (int ct = 0; ct < 4; ++ct) acc[rt][ct] = (f32x4){0.f, 0.f, 0.f, 0.f};

  #pragma unroll
  for (int kc = 0; kc < 4; ++kc){
    short8 ah[4], al[4], bh[4], bl[4];
    #pragma unroll
    for (int rt = 0; rt < 4; ++rt){
      ah[rt] = AH[ar[rt] * 16 + kc * 4 + q];
      al[rt] = AL[ar[rt] * 16 + kc * 4 + q];
    }
    #pragma unroll
    for (int ct = 0; ct < 4; ++ct){
      int wr = c0 + ct * 16 + l16;
      bh[ct] = B1H[wr * 16 + kc * 4 + q];
      bl[ct] = B1L[wr * 16 + kc * 4 + q];
    }
    #pragma unroll
    for (int rt = 0; rt < 4; ++rt)
      #pragma unroll
      for (int ct = 0; ct < 4; ++ct){
        acc[rt][ct] = __builtin_amdgcn_mfma_f32_16x16x32_bf16(ah[rt], bh[ct], acc[rt][ct], 0, 0, 0);
        acc[rt][ct] = __builtin_amdgcn_mfma_f32_16x16x32_bf16(ah[rt], bl[ct], acc[rt][ct], 0, 0, 0);
        acc[rt][ct] = __builtin_amdgcn_mfma_f32_16x16x32_bf16(al[rt], bh[ct], acc[rt][ct], 0, 0, 0);
      }
  }

  // ---- BN1 + ReLU -> H into LDS (hi/lo split) ----
  #pragma unroll
  for (int ct = 0; ct < 4; ++ct){
    int col = c0 + ct * 16 + l16;
    float s = sc1[col], b = sh1[col];
    #pragma unroll
    for (int rt = 0; rt < 4; ++rt)
      #pragma unroll
      for (int r = 0; r < 4; ++r){
        int rl = rt * 16 + q * 4 + r;       // C/D layout: row=(lane>>4)*4+reg
        float v = fmaxf(fmaf(acc[rt][ct][r], s, b), 0.f);
        unsigned short h = f2b(v);
        Hhi_s[rl * LSTR + col] = h;
        Hlo_s[rl * LSTR + col] = f2b(v - b2f(h));
      }
  }
  __syncthreads();   // H ready (both waves' column halves)

  // ---- gemm2: H from LDS, W2 from global/L2 ----
  f32x4 acc2[4][4];
  #pragma unroll
  for (int rt = 0; rt < 4; ++rt)
    #pragma unroll
    for (int ct = 0; ct < 4; ++ct) acc2[rt][ct] = (f32x4){0.f, 0.f, 0.f, 0.f};

  #pragma unroll
  for (int kc = 0; kc < 4; ++kc){
    short8 ah[4], al[4], bh[4], bl[4];
    #pragma unroll
    for (int rt = 0; rt < 4; ++rt){
      ah[rt] = *(const short8*)&Hhi_s[(rt * 16 + l16) * LSTR + kc * 32 + q * 8];
      al[rt] = *(const short8*)&Hlo_s[(rt * 16 + l16) * LSTR + kc * 32 + q * 8];
    }
    #pragma unroll
    for (int ct = 0; ct < 4; ++ct){
      int wr = c0 + ct * 16 + l16;
      bh[ct] = B2H[wr * 16 + kc * 4 + q];
      bl[ct] = B2L[wr * 16 + kc * 4 + q];
    }
    #pragma unroll
    for (int rt = 0; rt < 4; ++rt)
      #pragma unroll
      for (int ct = 0; ct < 4; ++ct){
        acc2[rt][ct] = __builtin_amdgcn_mfma_f32_16x16x32_bf16(ah[rt], bh[ct], acc2[rt][ct], 0, 0, 0);
        acc2[rt][ct] = __builtin_amdgcn_mfma_f32_16x16x32_bf16(ah[rt], bl[ct], acc2[rt][ct], 0, 0, 0);
        acc2[rt][ct] = __builtin_amdgcn_mfma_f32_16x16x32_bf16(al[rt], bh[ct], acc2[rt][ct], 0, 0, 0);
      }
  }
  __syncthreads();   // both waves done reading H; LDS reusable for staging

  // ---- epilogue: BN2 + ReLU; wave-private col-half staging, coalesced store ----
  if (!LAST){
    #pragma unroll
    for (int ct = 0; ct < 4; ++ct){
      int col = c0 + ct * 16 + l16;
      float s = sc2[col], b = sh2[col];
      #pragma unroll
      for (int rt = 0; rt < 4; ++rt)
        #pragma unroll
        for (int r = 0; r < 4; ++r){
          int rl = rt * 16 + q * 4 + r;
          float v = fmaxf(fmaf(acc2[rt][ct][r], s, b), 0.f);
          unsigned short h = f2b(v);
          Hhi_s[rl * LSTR + col] = h;
          Hlo_s[rl * LSTR + col] = f2b(v - b2f(h));
        }
    }
    // wave-private readback: 64 rows x own 64-col half
    int rr = lane >> 3, ch = lane & 7;
    #pragma unroll
    for (int i = 0; i < 8; ++i){
      int rl = i * 8 + rr;
      int rg = base + rl;
      short8 vh = *(const short8*)&Hhi_s[rl * LSTR + c0 + ch * 8];
      short8 vl = *(const short8*)&Hlo_s[rl * LSTR + c0 + ch * 8];
      if (rg < NN){
        *(short8*)&Ohi[rg * DD + c0 + ch * 8] = vh;
        *(short8*)&Olo[rg * DD + c0 + ch * 8] = vl;
      }
    }
  } else {
    float* Cf = (float*)smem;      // 64 x 132 floats = 33,792 B (fits)
    #pragma unroll
    for (int ct = 0; ct < 4; ++ct){
      int col = c0 + ct * 16 + l16;
      float s = sc2[col], b = sh2[col];
      #pragma unroll
      for (int rt = 0; rt < 4; ++rt)
        #pragma unroll
        for (int r = 0; r < 4; ++r){
          int rl = rt * 16 + q * 4 + r;
          Cf[rl * 132 + col] = fmaxf(fmaf(acc2[rt][ct][r], s, b), 0.f);
        }
    }
    int rr = lane >> 4, cf = (lane & 15) * 4;
    #pragma unroll
    for (int i = 0; i < 16; ++i){
      int rl = i * 4 + rr;
      int rg = base + rl;
      float4 v = *(const float4*)&Cf[rl * 132 + c0 + cf];
      if (rg < NN) *(float4*)&Of[rg * DD + c0 + cf] = v;
    }
  }
}

// ---------- launch ----------
extern "C" void kernel_launch(void* const* d_in, const int* in_sizes, int n_in,
                              void* d_out, int out_size, void* d_ws, size_t ws_size,
                              hipStream_t stream) {
  const float* x  = (const float*)d_in[0];
  const int* ei   = (const int*)d_in[1];
  const float* W1 = (const float*)d_in[2];
  const float* b1 = (const float*)d_in[3];
  const float* W2 = (const float*)d_in[4];
  const float* b2 = (const float*)d_in[5];
  const float* g  = (const float*)d_in[6];
  const float* be = (const float*)d_in[7];
  const float* rm = (const float*)d_in[8];
  const float* rv = (const float*)d_in[9];

  const int* src = ei;
  const int* dst = ei + NE;

  char* w = (char*)d_ws;
  const size_t HB = (size_t)NN * DD * sizeof(unsigned short);  // 12.8 MB
  unsigned short* S0hi = (unsigned short*)w; w += HB;
  unsigned short* S0lo = (unsigned short*)w; w += HB;
  unsigned short* S1hi = (unsigned short*)w; w += HB;
  unsigned short* S1lo = (unsigned short*)w; w += HB;
  unsigned short* Ahi  = (unsigned short*)w; w += HB;   // agg output
  unsigned short* Alo  = (unsigned short*)w; w += HB;
  unsigned short* Wthi = (unsigned short*)w; w += 6 * 16384 * sizeof(unsigned short);
  unsigned short* Wtlo = (unsigned short*)w; w += 6 * 16384 * sizeof(unsigned short);
  float* scv = (float*)w; w += NL * 2 * DD * sizeof(float);
  float* shv = (float*)w; w += NL * 2 * DD * sizeof(float);
  int* counts  = (int*)w; w += 200192;
  int* offs    = (int*)w; w += 200192;
  int* blkhist = (int*)w; w += MH * sizeof(int);
  int* pos     = (int*)w; w += MH * sizeof(int);
  int* bsum    = (int*)w; w += 1024;
  unsigned int* binned = (unsigned int*)w; w += (size_t)NE * sizeof(unsigned int);
  int* csr_src = (int*)w; w += (size_t)NE * sizeof(int);

  // CSR build: deterministic two-level binning (no cross-XCD line sharing)
  const int SCAN_BLK = (MH + 255) / 256;   // 154
  k_hist<<<NB_E, 256, 0, stream>>>(dst, blkhist);
  k_scanA<<<SCAN_BLK, 256, 0, stream>>>(blkhist, pos, bsum, MH);
  k_scanB<<<1, 256, 0, stream>>>(bsum, SCAN_BLK);
  k_scanC<<<SCAN_BLK, 256, 0, stream>>>(pos, bsum, MH);
  k_bin<<<NB_E, 256, 0, stream>>>(src, dst, pos, binned);
  k_csr<<<NBK, 256, 0, stream>>>(binned, pos, offs, counts, csr_src);

  // merged prep: x split + W transpose/split + BN fold
  k_prep<<<NN * DD / 8 / 256, 256, 0, stream>>>(x, W1, W2, b1, b2, g, be, rm, rv,
      S0hi, S0lo, Wthi, Wtlo, scv, shv);

  const int AGG_BLOCKS = NN * 16 / 256;      // 3125
  const int MLP_BLOCKS = (NN + 63) / 64;     // 782

  for (int i = 0; i < NL; ++i){
    const unsigned short* W1h = Wthi + (size_t)(i * 2 + 0) * 16384;
    const unsigned short* W1l = Wtlo + (size_t)(i * 2 + 0) * 16384;
    const unsigned short* W2h = Wthi + (size_t)(i * 2 + 1) * 16384;
    const unsigned short* W2l = Wtlo + (size_t)(i * 2 + 1) * 16384;
    const float* sc1 = scv + (size_t)(i * 2 + 0) * DD;
    const float* sh1 = shv + (size_t)(i * 2 + 0) * DD;
    const float* sc2 = scv + (size_t)(i * 2 + 1) * DD;
    const float* sh2 = shv + (size_t)(i * 2 + 1) * DD;

    const unsigned short* Ih = (i & 1) ? S1hi : S0hi;
    const unsigned short* Il = (i & 1) ? S1lo : S0lo;
    unsigned short* Oh = (i & 1) ? S0hi : S1hi;
    unsigned short* Ol = (i & 1) ? S0lo : S1lo;

    k_agg<<<AGG_BLOCKS, 256, 0, stream>>>(Ih, Il, offs, counts, csr_src, Ahi, Alo);

    if (i == NL - 1){
      k_mlp<1><<<MLP_BLOCKS, 128, 0, stream>>>(Ahi, Alo,
          W1h, W1l, W2h, W2l, sc1, sh1, sc2, sh2,
          (unsigned short*)nullptr, (unsigned short*)nullptr, (float*)d_out);
    } else {
      k_mlp<0><<<MLP_BLOCKS, 128, 0, stream>>>(Ahi, Alo,
          W1h, W1l, W2h, W2l, sc1, sh1, sc2, sh2, Oh, Ol, (float*)nullptr);
    }
  }
}

// Round 14
// 313.472 us; speedup vs baseline: 1.2743x; 1.0095x over previous
//
#include <hip/hip_runtime.h>
#include <stdint.h>

#define NN 50000
#define NE 800000
#define DD 128
#define NL 3
#define NB_E 200     // edge blocks for hist/bin
#define EPB 4000     // edges per block (NB_E*EPB == NE)
#define NBK 196      // dst buckets = ceil(NN/256), bucket = dst>>8
#define MH (NBK*NB_E)// blkhist elements = 39200
#define SCAN_BLK 154 // ceil(MH/256)
#define LSTR 136     // LDS ushort stride per row (272 B, 16B-aligned)

typedef __attribute__((ext_vector_type(8))) short short8;
typedef __attribute__((ext_vector_type(4))) float f32x4;

// ---------- bf16 helpers ----------
__device__ __forceinline__ float b2f(unsigned short u){
  union { unsigned int i; float f; } v; v.i = ((unsigned int)u) << 16; return v.f;
}
__device__ __forceinline__ unsigned short f2b(float f){
  union { float f; unsigned int i; } v; v.f = f;
  unsigned int r = 0x7FFFu + ((v.i >> 16) & 1u);
  return (unsigned short)((v.i + r) >> 16);
}

// ---------- front: hist (blocks 0..NB_E-1) + prep (blocks NB_E..) ----------
__global__ __launch_bounds__(256) void k_front(const int* __restrict__ dst,
    int* __restrict__ blkhist,
    const float* __restrict__ x,
    const float* __restrict__ W1, const float* __restrict__ W2,
    const float* __restrict__ b1, const float* __restrict__ b2,
    const float* __restrict__ g, const float* __restrict__ be,
    const float* __restrict__ rm, const float* __restrict__ rv,
    unsigned short* __restrict__ Shi, unsigned short* __restrict__ Slo,
    unsigned short* __restrict__ Wthi, unsigned short* __restrict__ Wtlo,
    float* __restrict__ sc, float* __restrict__ sh){
  __shared__ int h[NBK];
  int t = threadIdx.x;
  if (blockIdx.x < NB_E){
    // ---- histogram over dst buckets ----
    int b = blockIdx.x;
    for (int i = t; i < NBK; i += 256) h[i] = 0;
    __syncthreads();
    int e0 = b * EPB;
    for (int i = t; i < EPB; i += 256){
      int d = dst[e0 + i];
      atomicAdd(&h[d >> 8], 1);
    }
    __syncthreads();
    for (int i = t; i < NBK; i += 256) blkhist[i * NB_E + b] = h[i];
    return;
  }
  // ---- prep: x split + W transpose/split + BN fold ----
  int idx = (blockIdx.x - NB_E) * 256 + t;    // 0 .. NN*DD/8-1 (800000)
  {
    float4 a = ((const float4*)x)[2 * idx];
    float4 b = ((const float4*)x)[2 * idx + 1];
    float v[8] = {a.x, a.y, a.z, a.w, b.x, b.y, b.z, b.w};
    short8 h8, l8;
    #pragma unroll
    for (int c = 0; c < 8; ++c){
      unsigned short hh = f2b(v[c]);
      h8[c] = (short)hh; l8[c] = (short)f2b(v[c] - b2f(hh));
    }
    ((short8*)Shi)[idx] = h8;
    ((short8*)Slo)[idx] = l8;
  }
  if (idx < 6 * DD * DD){
    int mat = idx >> 14;
    int rem = idx & 16383;
    int k = rem >> 7, j = rem & 127;
    int layer = mat >> 1, which = mat & 1;
    const float* srcW = which ? W2 : W1;
    float w = srcW[layer * 16384 + k * DD + j];
    unsigned short hi = f2b(w);
    Wthi[mat * 16384 + j * DD + k] = hi;
    Wtlo[mat * 16384 + j * DD + k] = f2b(w - b2f(hi));
  }
  if (idx < NL * 2 * DD){
    int j = idx & 127;
    int w2 = (idx >> 7) & 1;
    int l = idx >> 8;
    int p = (l * 2 + w2) * DD + j;
    float s = g[p] * rsqrtf(rv[p] + 1e-5f);
    float bias = w2 ? b2[l * DD + j] : b1[l * DD + j];
    sc[p] = s;
    sh[p] = fmaf(bias - rm[p], s, be[p]);
  }
}

// ---------- scan: per-block exclusive prefix + raw block sums ----------
__global__ void k_scan(const int* __restrict__ in, int* __restrict__ out,
                       int* __restrict__ bsum){
  __shared__ int s[256];
  int t = threadIdx.x, i = blockIdx.x * 256 + t;
  int v = (i < MH) ? in[i] : 0;
  s[t] = v; __syncthreads();
  for (int d = 1; d < 256; d <<= 1){
    int x = (t >= d) ? s[t - d] : 0;
    __syncthreads();
    s[t] += x;
    __syncthreads();
  }
  if (i < MH) out[i] = s[t] - v;            // within-block exclusive
  if (t == 255) bsum[blockIdx.x] = s[255];  // raw block total
}

// helper: LDS exclusive scan of bsum[SCAN_BLK] -> ex[]; call with 256 threads
__device__ __forceinline__ void scan_bsum(const int* __restrict__ bsum, int* ex, int t){
  __shared__ int s[256];
  int v = (t < SCAN_BLK) ? bsum[t] : 0;
  s[t] = v; __syncthreads();
  for (int d = 1; d < 256; d <<= 1){
    int x = (t >= d) ? s[t - d] : 0;
    __syncthreads();
    s[t] += x;
    __syncthreads();
  }
  ex[t] = s[t] - v;                         // exclusive
  __syncthreads();
}

// ---------- bin: scatter edges into bucket-grouped runs ----------
__global__ __launch_bounds__(256) void k_bin(const int* __restrict__ src,
    const int* __restrict__ dst, const int* __restrict__ pos,
    const int* __restrict__ bsum, unsigned int* __restrict__ binned){
  __shared__ int ex[256];
  __shared__ int cur[NBK];
  int t = threadIdx.x, b = blockIdx.x;
  scan_bsum(bsum, ex, t);
  for (int i = t; i < NBK; i += 256){
    int idx = i * NB_E + b;
    cur[i] = pos[idx] + ex[idx >> 8];
  }
  __syncthreads();
  int e0 = b * EPB;
  for (int i = t; i < EPB; i += 256){
    int d = dst[e0 + i];
    int s = src[e0 + i];
    int p = atomicAdd(&cur[d >> 8], 1);
    binned[p] = ((unsigned int)d << 16) | (unsigned int)s;
  }
}

// ---------- csr: one block per bucket; exclusive owner of its region ----------
__global__ __launch_bounds__(256) void k_csr(const unsigned int* __restrict__ binned,
    const int* __restrict__ pos, const int* __restrict__ bsum,
    int* __restrict__ offs, int* __restrict__ counts, int* __restrict__ csr_src){
  __shared__ int exb[256];
  __shared__ int h[256], ex[256], cur[256];
  int t = threadIdx.x, b = blockIdx.x;
  scan_bsum(bsum, exb, t);
  int i0 = b * NB_E;
  int r0 = pos[i0] + exb[i0 >> 8];
  int r1 = NE;
  if (b < NBK - 1){
    int i1 = (b + 1) * NB_E;
    r1 = pos[i1] + exb[i1 >> 8];
  }
  h[t] = 0; __syncthreads();
  for (int i = r0 + t; i < r1; i += 256){
    unsigned int pv = binned[i];
    atomicAdd(&h[(pv >> 16) & 255], 1);
  }
  __syncthreads();
  int v = h[t];
  ex[t] = v; __syncthreads();
  for (int d = 1; d < 256; d <<= 1){
    int x = (t >= d) ? ex[t - d] : 0;
    __syncthreads();
    ex[t] += x;
    __syncthreads();
  }
  int base = r0 + ex[t] - v;
  cur[t] = base;
  int gd = b * 256 + t;
  if (gd < NN){ offs[gd] = base; counts[gd] = v; }
  __syncthreads();
  for (int i = r0 + t; i < r1; i += 256){
    unsigned int pv = binned[i];
    int dl = (pv >> 16) & 255;
    int s = pv & 0xFFFF;
    int p = atomicAdd(&cur[dl], 1);
    csr_src[p] = s;
  }
}

// ---------- aggregate (standalone, max occupancy): 16 lanes/row, 8-nbr unroll ----------
__global__ __launch_bounds__(256, 8) void k_agg(
    const unsigned short* __restrict__ Shi, const unsigned short* __restrict__ Slo,
    const int* __restrict__ offs, const int* __restrict__ counts,
    const int* __restrict__ csr_src,
    unsigned short* __restrict__ Ahi, unsigned short* __restrict__ Alo){
  int t = blockIdx.x * 256 + threadIdx.x;
  int row = t >> 4;                // grid 3125 covers exactly NN
  int l = t & 15;
  const short8* H = (const short8*)Shi;   // [row][16]
  const short8* L = (const short8*)Slo;
  int idx = row * 16 + l;
  short8 s_h = H[idx]; short8 s_l = L[idx];
  float acc[8];
  #pragma unroll
  for (int i = 0; i < 8; ++i)
    acc[i] = b2f((unsigned short)s_h[i]) + b2f((unsigned short)s_l[i]);

  int e = offs[row];
  int end = e + counts[row];
  for (; e + 8 <= end; e += 8){
    int i0 = csr_src[e],   i1 = csr_src[e+1], i2 = csr_src[e+2], i3 = csr_src[e+3];
    int i4 = csr_src[e+4], i5 = csr_src[e+5], i6 = csr_src[e+6], i7 = csr_src[e+7];
    short8 g0 = H[i0*16+l], g1 = H[i1*16+l], g2 = H[i2*16+l], g3 = H[i3*16+l];
    short8 g4 = H[i4*16+l], g5 = H[i5*16+l], g6 = H[i6*16+l], g7 = H[i7*16+l];
    #pragma unroll
    for (int i = 0; i < 8; ++i){
      acc[i] += (b2f((unsigned short)g0[i]) + b2f((unsigned short)g1[i]))
              + (b2f((unsigned short)g2[i]) + b2f((unsigned short)g3[i]))
              + (b2f((unsigned short)g4[i]) + b2f((unsigned short)g5[i]))
              + (b2f((unsigned short)g6[i]) + b2f((unsigned short)g7[i]));
    }
  }
  for (; e < end; ++e){
    short8 g0 = H[csr_src[e]*16 + l];
    #pragma unroll
    for (int i = 0; i < 8; ++i) acc[i] += b2f((unsigned short)g0[i]);
  }

  short8 oh, ol;
  #pragma unroll
  for (int i = 0; i < 8; ++i){
    unsigned short h = f2b(acc[i]);
    oh[i] = (short)h; ol[i] = (short)f2b(acc[i] - b2f(h));
  }
  ((short8*)Ahi)[idx] = oh;
  ((short8*)Alo)[idx] = ol;
}

// ---------- fused MLP: 128-thr block = 2 waves; 64 rows x 64 cols/wave ----------
// gemm1 reads A DIRECT from global (fragment = contiguous 16B). LDS (34.8KB) only for
// H handoff + epilogue staging. 2 barriers total. 16 acc chains/wave.
template<int LAST>
__global__ __launch_bounds__(128, 2) void k_mlp(
    const unsigned short* __restrict__ Ahi, const unsigned short* __restrict__ Alo,
    const unsigned short* __restrict__ W1h, const unsigned short* __restrict__ W1l,
    const unsigned short* __restrict__ W2h, const unsigned short* __restrict__ W2l,
    const float* __restrict__ sc1, const float* __restrict__ sh1,
    const float* __restrict__ sc2, const float* __restrict__ sh2,
    unsigned short* __restrict__ Ohi, unsigned short* __restrict__ Olo,
    float* __restrict__ Of)
{
  __shared__ __align__(16) char smem[2 * 64 * LSTR * 2];   // 34,816 B (H hi/lo; C stage)
  unsigned short* Hhi_s = (unsigned short*)smem;
  unsigned short* Hlo_s = Hhi_s + 64 * LSTR;

  int t = threadIdx.x;
  int base = blockIdx.x * 64;
  int wave = t >> 6, lane = t & 63, l16 = lane & 15, q = lane >> 4;
  int c0 = wave * 64;            // this wave's 64 output cols

  const short8* AH = (const short8*)Ahi;    // [row][16]
  const short8* AL = (const short8*)Alo;
  const short8* B1H = (const short8*)W1h;   // [j][16]
  const short8* B1L = (const short8*)W1l;
  const short8* B2H = (const short8*)W2h;
  const short8* B2L = (const short8*)W2l;

  int ar[4];
  #pragma unroll
  for (int rt = 0; rt < 4; ++rt){
    int r = base + rt * 16 + l16;
    ar[rt] = (r > NN - 1) ? (NN - 1) : r;
  }

  // ---- gemm1: A direct from global, W1 from global/L2 ----
  f32x4 acc[4][4];
  #pragma unroll
  for (int rt = 0; rt < 4; ++rt)
    #pragma unroll
    for (int ct = 0; ct < 4; ++ct) acc[rt][ct] = (f32x4){0.f, 0.f, 0.f, 0.f};

  #pragma unroll
  for (int kc = 0; kc < 4; ++kc){
    short8 ah[4], al[4], bh[4], bl[4];
    #pragma unroll
    for (int rt = 0; rt < 4; ++rt){
      ah[rt] = AH[ar[rt] * 16 + kc * 4 + q];
      al[rt] = AL[ar[rt] * 16 + kc * 4 + q];
    }
    #pragma unroll
    for (int ct = 0; ct < 4; ++ct){
      int wr = c0 + ct * 16 + l16;
      bh[ct] = B1H[wr * 16 + kc * 4 + q];
      bl[ct] = B1L[wr * 16 + kc * 4 + q];
    }
    #pragma unroll
    for (int rt = 0; rt < 4; ++rt)
      #pragma unroll
      for (int ct = 0; ct < 4; ++ct){
        acc[rt][ct] = __builtin_amdgcn_mfma_f32_16x16x32_bf16(ah[rt], bh[ct], acc[rt][ct], 0, 0, 0);
        acc[rt][ct] = __builtin_amdgcn_mfma_f32_16x16x32_bf16(ah[rt], bl[ct], acc[rt][ct], 0, 0, 0);
        acc[rt][ct] = __builtin_amdgcn_mfma_f32_16x16x32_bf16(al[rt], bh[ct], acc[rt][ct], 0, 0, 0);
      }
  }

  // ---- BN1 + ReLU -> H into LDS (hi/lo split) ----
  #pragma unroll
  for (int ct = 0; ct < 4; ++ct){
    int col = c0 + ct * 16 + l16;
    float s = sc1[col], b = sh1[col];
    #pragma unroll
    for (int rt = 0; rt < 4; ++rt)
      #pragma unroll
      for (int r = 0; r < 4; ++r){
        int rl = rt * 16 + q * 4 + r;       // C/D layout: row=(lane>>4)*4+reg
        float v = fmaxf(fmaf(acc[rt][ct][r], s, b), 0.f);
        unsigned short h = f2b(v);
        Hhi_s[rl * LSTR + col] = h;
        Hlo_s[rl * LSTR + col] = f2b(v - b2f(h));
      }
  }
  __syncthreads();   // H ready (both waves' column halves)

  // ---- gemm2: H from LDS, W2 from global/L2 ----
  f32x4 acc2[4][4];
  #pragma unroll
  for (int rt = 0; rt < 4; ++rt)
    #pragma unroll
    for (int ct = 0; ct < 4; ++ct) acc2[rt][ct] = (f32x4){0.f, 0.f, 0.f, 0.f};

  #pragma unroll
  for (int kc = 0; kc < 4; ++kc){
    short8 ah[4], al[4], bh[4], bl[4];
    #pragma unroll
    for (int rt = 0; rt < 4; ++rt){
      ah[rt] = *(const short8*)&Hhi_s[(rt * 16 + l16) * LSTR + kc * 32 + q * 8];
      al[rt] = *(const short8*)&Hlo_s[(rt * 16 + l16) * LSTR + kc * 32 + q * 8];
    }
    #pragma unroll
    for (int ct = 0; ct < 4; ++ct){
      int wr = c0 + ct * 16 + l16;
      bh[ct] = B2H[wr * 16 + kc * 4 + q];
      bl[ct] = B2L[wr * 16 + kc * 4 + q];
    }
    #pragma unroll
    for (int rt = 0; rt < 4; ++rt)
      #pragma unroll
      for (int ct = 0; ct < 4; ++ct){
        acc2[rt][ct] = __builtin_amdgcn_mfma_f32_16x16x32_bf16(ah[rt], bh[ct], acc2[rt][ct], 0, 0, 0);
        acc2[rt][ct] = __builtin_amdgcn_mfma_f32_16x16x32_bf16(ah[rt], bl[ct], acc2[rt][ct], 0, 0, 0);
        acc2[rt][ct] = __builtin_amdgcn_mfma_f32_16x16x32_bf16(al[rt], bh[ct], acc2[rt][ct], 0, 0, 0);
      }
  }
  __syncthreads();   // both waves done reading H; LDS reusable for staging

  // ---- epilogue: BN2 + ReLU; wave-private col-half staging, coalesced store ----
  if (!LAST){
    #pragma unroll
    for (int ct = 0; ct < 4; ++ct){
      int col = c0 + ct * 16 + l16;
      float s = sc2[col], b = sh2[col];
      #pragma unroll
      for (int rt = 0; rt < 4; ++rt)
        #pragma unroll
        for (int r = 0; r < 4; ++r){
          int rl = rt * 16 + q * 4 + r;
          float v = fmaxf(fmaf(acc2[rt][ct][r], s, b), 0.f);
          unsigned short h = f2b(v);
          Hhi_s[rl * LSTR + col] = h;
          Hlo_s[rl * LSTR + col] = f2b(v - b2f(h));
        }
    }
    // wave-private readback: 64 rows x own 64-col half
    int rr = lane >> 3, ch = lane & 7;
    #pragma unroll
    for (int i = 0; i < 8; ++i){
      int rl = i * 8 + rr;
      int rg = base + rl;
      short8 vh = *(const short8*)&Hhi_s[rl * LSTR + c0 + ch * 8];
      short8 vl = *(const short8*)&Hlo_s[rl * LSTR + c0 + ch * 8];
      if (rg < NN){
        *(short8*)&Ohi[rg * DD + c0 + ch * 8] = vh;
        *(short8*)&Olo[rg * DD + c0 + ch * 8] = vl;
      }
    }
  } else {
    float* Cf = (float*)smem;      // 64 x 132 floats = 33,792 B (fits)
    #pragma unroll
    for (int ct = 0; ct < 4; ++ct){
      int col = c0 + ct * 16 + l16;
      float s = sc2[col], b = sh2[col];
      #pragma unroll
      for (int rt = 0; rt < 4; ++rt)
        #pragma unroll
        for (int r = 0; r < 4; ++r){
          int rl = rt * 16 + q * 4 + r;
          Cf[rl * 132 + col] = fmaxf(fmaf(acc2[rt][ct][r], s, b), 0.f);
        }
    }
    int rr = lane >> 4, cf = (lane & 15) * 4;
    #pragma unroll
    for (int i = 0; i < 16; ++i){
      int rl = i * 4 + rr;
      int rg = base + rl;
      float4 v = *(const float4*)&Cf[rl * 132 + c0 + cf];
      if (rg < NN) *(float4*)&Of[rg * DD + c0 + cf] = v;
    }
  }
}

// ---------- launch ----------
extern "C" void kernel_launch(void* const* d_in, const int* in_sizes, int n_in,
                              void* d_out, int out_size, void* d_ws, size_t ws_size,
                              hipStream_t stream) {
  const float* x  = (const float*)d_in[0];
  const int* ei   = (const int*)d_in[1];
  const float* W1 = (const float*)d_in[2];
  const float* b1 = (const float*)d_in[3];
  const float* W2 = (const float*)d_in[4];
  const float* b2 = (const float*)d_in[5];
  const float* g  = (const float*)d_in[6];
  const float* be = (const float*)d_in[7];
  const float* rm = (const float*)d_in[8];
  const float* rv = (const float*)d_in[9];

  const int* src = ei;
  const int* dst = ei + NE;

  char* w = (char*)d_ws;
  const size_t HB = (size_t)NN * DD * sizeof(unsigned short);  // 12.8 MB
  unsigned short* S0hi = (unsigned short*)w; w += HB;
  unsigned short* S0lo = (unsigned short*)w; w += HB;
  unsigned short* S1hi = (unsigned short*)w; w += HB;
  unsigned short* S1lo = (unsigned short*)w; w += HB;
  unsigned short* Ahi  = (unsigned short*)w; w += HB;   // agg output
  unsigned short* Alo  = (unsigned short*)w; w += HB;
  unsigned short* Wthi = (unsigned short*)w; w += 6 * 16384 * sizeof(unsigned short);
  unsigned short* Wtlo = (unsigned short*)w; w += 6 * 16384 * sizeof(unsigned short);
  float* scv = (float*)w; w += NL * 2 * DD * sizeof(float);
  float* shv = (float*)w; w += NL * 2 * DD * sizeof(float);
  int* counts  = (int*)w; w += 200192;
  int* offs    = (int*)w; w += 200192;
  int* blkhist = (int*)w; w += MH * sizeof(int);
  int* pos     = (int*)w; w += MH * sizeof(int);
  int* bsum    = (int*)w; w += 1024;
  unsigned int* binned = (unsigned int*)w; w += (size_t)NE * sizeof(unsigned int);
  int* csr_src = (int*)w; w += (size_t)NE * sizeof(int);

  // front: hist + prep merged (independent, block-range split)
  k_front<<<NB_E + NN * DD / 8 / 256, 256, 0, stream>>>(dst, blkhist,
      x, W1, W2, b1, b2, g, be, rm, rv, S0hi, S0lo, Wthi, Wtlo, scv, shv);

  // CSR build: scan (per-block prefix + raw sums); consumers scan bsum inline
  k_scan<<<SCAN_BLK, 256, 0, stream>>>(blkhist, pos, bsum);
  k_bin<<<NB_E, 256, 0, stream>>>(src, dst, pos, bsum, binned);
  k_csr<<<NBK, 256, 0, stream>>>(binned, pos, bsum, offs, counts, csr_src);

  const int AGG_BLOCKS = NN * 16 / 256;      // 3125
  const int MLP_BLOCKS = (NN + 63) / 64;     // 782

  for (int i = 0; i < NL; ++i){
    const unsigned short* W1h = Wthi + (size_t)(i * 2 + 0) * 16384;
    const unsigned short* W1l = Wtlo + (size_t)(i * 2 + 0) * 16384;
    const unsigned short* W2h = Wthi + (size_t)(i * 2 + 1) * 16384;
    const unsigned short* W2l = Wtlo + (size_t)(i * 2 + 1) * 16384;
    const float* sc1 = scv + (size_t)(i * 2 + 0) * DD;
    const float* sh1 = shv + (size_t)(i * 2 + 0) * DD;
    const float* sc2 = scv + (size_t)(i * 2 + 1) * DD;
    const float* sh2 = shv + (size_t)(i * 2 + 1) * DD;

    const unsigned short* Ih = (i & 1) ? S1hi : S0hi;
    const unsigned short* Il = (i & 1) ? S1lo : S0lo;
    unsigned short* Oh = (i & 1) ? S0hi : S1hi;
    unsigned short* Ol = (i & 1) ? S0lo : S1lo;

    k_agg<<<AGG_BLOCKS, 256, 0, stream>>>(Ih, Il, offs, counts, csr_src, Ahi, Alo);

    if (i == NL - 1){
      k_mlp<1><<<MLP_BLOCKS, 128, 0, stream>>>(Ahi, Alo,
          W1h, W1l, W2h, W2l, sc1, sh1, sc2, sh2,
          (unsigned short*)nullptr, (unsigned short*)nullptr, (float*)d_out);
    } else {
      k_mlp<0><<<MLP_BLOCKS, 128, 0, stream>>>(Ahi, Alo,
          W1h, W1l, W2h, W2l, sc1, sh1, sc2, sh2, Oh, Ol, (float*)nullptr);
    }
  }
}